// Round 2
// baseline (1503.836 us; speedup 1.0000x reference)
//
#include <hip/hip_runtime.h>
#include <hip/hip_bf16.h>

typedef unsigned short u16;
typedef unsigned int   u32;

#define MP     3328          // padded token rows (26*128)
#define MREAL  3140          // B*N = 4*785
#define DIMC   1024
#define H3C    3072
#define HIDC   4096
#define NKV    785
#define SLEN   896           // padded score row length (7*128)

typedef __bf16 bf16x8 __attribute__((ext_vector_type(8)));
typedef float  f32x4  __attribute__((ext_vector_type(4)));

#define MFMA(d,a,b) (d) = __builtin_amdgcn_mfma_f32_16x16x32_bf16((a),(b),(d),0,0,0)

__device__ __forceinline__ u16 f2bf(float f){
  u32 u = __builtin_bit_cast(u32, f);
  return (u16)((u + 0x7fffu + ((u >> 16) & 1u)) >> 16);
}
__device__ __forceinline__ float bf2f(u16 h){
  return __builtin_bit_cast(float, (u32)h << 16);
}
__device__ __forceinline__ void gload16(const u16* g, u16* l){
  __builtin_amdgcn_global_load_lds(
      (const __attribute__((address_space(1))) void*)g,
      (__attribute__((address_space(3))) void*)l, 16, 0, 0);
}
__device__ __forceinline__ float wsum(float v){
  #pragma unroll
  for (int o = 32; o >= 1; o >>= 1) v += __shfl_xor(v, o);
  return v;
}
__device__ __forceinline__ float wmax(float v){
  #pragma unroll
  for (int o = 32; o >= 1; o >>= 1) v = fmaxf(v, __shfl_xor(v, o));
  return v;
}

// ---------------- fp32 -> bf16 weight conversion ----------------
__global__ __launch_bounds__(256) void cvt_k(const float* __restrict__ in,
                                             u16* __restrict__ out, int n){
  int i = (blockIdx.x * 256 + threadIdx.x) * 4;
  if (i >= n) return;
  float4 v = *(const float4*)(in + i);
  ushort4 o4;
  o4.x = f2bf(v.x); o4.y = f2bf(v.y); o4.z = f2bf(v.z); o4.w = f2bf(v.w);
  *(ushort4*)(out + i) = o4;
}

// ---------------- LayerNorm + JVP (fp32 in -> bf16 out, zero pad rows) -----
__global__ __launch_bounds__(256) void ln_jvp_k(
    const float* __restrict__ x, const float* __restrict__ xj,
    const float* __restrict__ w, const float* __restrict__ b,
    const float* __restrict__ lw, const float* __restrict__ lb,
    u16* __restrict__ out, u16* __restrict__ outj)
{
  const int row = blockIdx.x, t = threadIdx.x;
  const size_t ro = (size_t)row * DIMC;
  if (row >= MREAL){
    for (int i = t; i < DIMC; i += 256){ out[ro+i] = 0; outj[ro+i] = 0; }
    return;
  }
  const float4 v  = ((const float4*)(x  + ro))[t];
  const float4 vj = ((const float4*)(xj + ro))[t];
  float sx  = v.x+v.y+v.z+v.w;
  float sxx = v.x*v.x+v.y*v.y+v.z*v.z+v.w*v.w;
  float sj  = vj.x+vj.y+vj.z+vj.w;
  float sxj = v.x*vj.x+v.y*vj.y+v.z*vj.z+v.w*vj.w;
  __shared__ __attribute__((aligned(64))) float red[4][4];
  sx = wsum(sx); sxx = wsum(sxx); sj = wsum(sj); sxj = wsum(sxj);
  const int wid = t>>6, lane = t&63;
  if (lane == 0){ red[wid][0]=sx; red[wid][1]=sxx; red[wid][2]=sj; red[wid][3]=sxj; }
  __syncthreads();
  sx  = red[0][0]+red[1][0]+red[2][0]+red[3][0];
  sxx = red[0][1]+red[1][1]+red[2][1]+red[3][1];
  sj  = red[0][2]+red[1][2]+red[2][2]+red[3][2];
  sxj = red[0][3]+red[1][3]+red[2][3]+red[3][3];
  const float inv  = 1.0f/1024.0f;
  const float mean = sx*inv, meanj = sj*inv;
  const float var  = sxx*inv - mean*mean;
  const float cov  = sxj*inv - mean*meanj;       // mean(xc*xjc)
  const float rstd = rsqrtf(var + 1e-5f);
  const float r3   = rstd*rstd*rstd;
  const float4 wv  = ((const float4*)w)[t];
  const float4 bv  = ((const float4*)b)[t];
  const float4 lwv = ((const float4*)lw)[t];
  const float4 lbv = ((const float4*)lb)[t];
  const float xs[4]  = {v.x,v.y,v.z,v.w},   xjs[4] = {vj.x,vj.y,vj.z,vj.w};
  const float wss[4] = {wv.x,wv.y,wv.z,wv.w}, bs[4] = {bv.x,bv.y,bv.z,bv.w};
  const float lws[4] = {lwv.x,lwv.y,lwv.z,lwv.w}, lbs[4] = {lbv.x,lbv.y,lbv.z,lbv.w};
  const int i0 = t*4;
  #pragma unroll
  for (int e = 0; e < 4; e++){
    const float xc = xs[e]-mean, xjc = xjs[e]-meanj;
    const float xhat = xc*rstd;
    const float cc = xjc*rstd - xc*cov*r3;       // == (1/std^2)(a - bterm)
    out [ro+i0+e] = f2bf(xhat*wss[e] + bs[e]);
    outj[ro+i0+e] = f2bf(xhat*lws[e] + lbs[e] + cc*wss[e]);
  }
}

// ---------------- fused JVP GEMM: Y = A*B^T (+epi), Yj = Aj*B^T + A*Bj^T ----
// A,Aj: [M,K] bf16 row-major (M padded to mult of 128). B,Bj: [N,K] bf16.
// EPI 0: write Y,Yj bf16 (ld=ldy), unpredicated (padded dest).
// EPI 1: Y,Yj fp32 = acc + bias + res (res ld = ldy), rows < mwrite only.
// EPI 2: GELU-JVP epilogue, bf16 out, unpredicated.
template<int EPI>
__global__ __launch_bounds__(256) void gemm_jvp_k(
    const u16* __restrict__ A, const u16* __restrict__ Aj, int lda,
    const u16* __restrict__ B, const u16* __restrict__ Bj, int K,
    const float* __restrict__ bias, const float* __restrict__ biasj,
    const float* __restrict__ res, const float* __restrict__ resj,
    void* __restrict__ Yv, void* __restrict__ Yjv, int ldy, int mwrite)
{
  __shared__ __attribute__((aligned(64))) u16 lA[128*32];
  __shared__ __attribute__((aligned(64))) u16 lAj[128*32];
  __shared__ __attribute__((aligned(64))) u16 lB[128*32];
  __shared__ __attribute__((aligned(64))) u16 lBj[128*32];
  const int tid = threadIdx.x, wid = tid>>6, lane = tid&63;
  const int m0 = blockIdx.y*128, n0 = blockIdx.x*128;
  f32x4 accY[4][4], accJ[4][4];
  #pragma unroll
  for (int i = 0; i < 4; i++)
    #pragma unroll
    for (int j = 0; j < 4; j++){
      accY[i][j] = (f32x4){0.f,0.f,0.f,0.f};
      accJ[i][j] = (f32x4){0.f,0.f,0.f,0.f};
    }
  const int bo0 = wid*1024 + lane*16;     // staging byte offset, round 0
  const int bo1 = bo0 + 4096;             // round 1
  const int r0 = bo0>>6, c0 = (bo0&63)>>1;
  const int r1 = bo1>>6, c1 = (bo1&63)>>1;
  const u16* A0  = A  + (size_t)(m0+r0)*lda + c0;
  const u16* A1  = A  + (size_t)(m0+r1)*lda + c1;
  const u16* Aj0 = Aj + (size_t)(m0+r0)*lda + c0;
  const u16* Aj1 = Aj + (size_t)(m0+r1)*lda + c1;
  const u16* B0  = B  + (size_t)(n0+r0)*K + c0;
  const u16* B1  = B  + (size_t)(n0+r1)*K + c1;
  const u16* Bj0 = Bj + (size_t)(n0+r0)*K + c0;
  const u16* Bj1 = Bj + (size_t)(n0+r1)*K + c1;
  for (int k0 = 0; k0 < K; k0 += 32){
    gload16(A0 +k0, lA +(bo0>>1));
    gload16(A1 +k0, lA +(bo1>>1));
    gload16(Aj0+k0, lAj+(bo0>>1));
    gload16(Aj1+k0, lAj+(bo1>>1));
    gload16(B0 +k0, lB +(bo0>>1));
    gload16(B1 +k0, lB +(bo1>>1));
    gload16(Bj0+k0, lBj+(bo0>>1));
    gload16(Bj1+k0, lBj+(bo1>>1));
    __syncthreads();
    const int kq = (lane>>4)<<3;
    const int ar = (wid>>1)*64 + (lane&15);
    const int bc = (wid&1)*64 + (lane&15);
    bf16x8 af[4], ajf[4], bbf[4], bjf[4];
    #pragma unroll
    for (int i = 0; i < 4; i++){
      af[i]  = *(const bf16x8*)(lA  + (ar+i*16)*32 + kq);
      ajf[i] = *(const bf16x8*)(lAj + (ar+i*16)*32 + kq);
      bbf[i] = *(const bf16x8*)(lB  + (bc+i*16)*32 + kq);
      bjf[i] = *(const bf16x8*)(lBj + (bc+i*16)*32 + kq);
    }
    #pragma unroll
    for (int i = 0; i < 4; i++)
      #pragma unroll
      for (int j = 0; j < 4; j++){
        MFMA(accY[i][j], af[i],  bbf[j]);
        MFMA(accJ[i][j], ajf[i], bbf[j]);
        MFMA(accJ[i][j], af[i],  bjf[j]);
      }
    __syncthreads();
  }
  const int mb = m0 + (wid>>1)*64 + ((lane>>4)<<2);
  const int nb = n0 + (wid&1)*64 + (lane&15);
  #pragma unroll
  for (int i = 0; i < 4; i++)
    #pragma unroll
    for (int j = 0; j < 4; j++)
      #pragma unroll
      for (int r = 0; r < 4; r++){
        const int m = mb + i*16 + r, n = nb + j*16;
        float y = accY[i][j][r], yj = accJ[i][j][r];
        if (EPI == 0){
          ((u16*)Yv )[(size_t)m*ldy+n] = f2bf(y);
          ((u16*)Yjv)[(size_t)m*ldy+n] = f2bf(yj);
        } else if (EPI == 1){
          if (m < mwrite){
            y  += bias[n]  + res [(size_t)m*ldy+n];
            yj += biasj[n] + resj[(size_t)m*ldy+n];
            ((float*)Yv )[(size_t)m*ldy+n] = y;
            ((float*)Yjv)[(size_t)m*ldy+n] = yj;
          }
        } else {
          y  += bias[n];
          yj += biasj[n];
          const float ge  = 0.5f*y*(1.0f + erff(y*0.70710678118654752f));
          const float pdf = expf(-0.5f*y*y)*0.3989422804014327f;
          const float gj  = yj*(ge/(y + 1e-8f) + y*pdf);
          ((u16*)Yv )[(size_t)m*ldy+n] = f2bf(ge);
          ((u16*)Yjv)[(size_t)m*ldy+n] = f2bf(gj);
        }
      }
}

// ---------------- attention scores: S = 0.125*Q*K^T, DM = 0.125*(Qj*K^T+Q*Kj^T)
// 4-head slab chunk: head = hbase + blockIdx.z, slab index = blockIdx.z.
__global__ __launch_bounds__(256) void attn_scores_k(
    const u16* __restrict__ qkvb, const u16* __restrict__ qkvjb,
    int bbase, int hbase, u16* __restrict__ S, u16* __restrict__ DMb)
{
  __shared__ __attribute__((aligned(64))) u16 lq[128*32];
  __shared__ __attribute__((aligned(64))) u16 lqj[128*32];
  __shared__ __attribute__((aligned(64))) u16 lk[128*32];
  __shared__ __attribute__((aligned(64))) u16 lkj[128*32];
  const int tid = threadIdx.x, wid = tid>>6, lane = tid&63;
  const int nt = blockIdx.x, mt = blockIdx.y, hz = blockIdx.z;
  const int h = hbase + hz;
  f32x4 accS[4][4], accD[4][4];
  #pragma unroll
  for (int i = 0; i < 4; i++)
    #pragma unroll
    for (int j = 0; j < 4; j++){
      accS[i][j] = (f32x4){0.f,0.f,0.f,0.f};
      accD[i][j] = (f32x4){0.f,0.f,0.f,0.f};
    }
  const int qoff = h*64, koff = 1024 + h*64;
  const int bo0 = wid*1024 + lane*16, bo1 = bo0 + 4096;
  const int r0 = bo0>>6, c0 = (bo0&63)>>1;
  const int r1 = bo1>>6, c1 = (bo1&63)>>1;
  const size_t qr0 = (size_t)(bbase+mt*128+r0)*H3C;
  const size_t qr1 = (size_t)(bbase+mt*128+r1)*H3C;
  const size_t kr0 = (size_t)(bbase+nt*128+r0)*H3C;
  const size_t kr1 = (size_t)(bbase+nt*128+r1)*H3C;
  for (int kh = 0; kh < 64; kh += 32){
    gload16(qkvb  + qr0 + qoff + kh + c0, lq +(bo0>>1));
    gload16(qkvb  + qr1 + qoff + kh + c1, lq +(bo1>>1));
    gload16(qkvjb + qr0 + qoff + kh + c0, lqj+(bo0>>1));
    gload16(qkvjb + qr1 + qoff + kh + c1, lqj+(bo1>>1));
    gload16(qkvb  + kr0 + koff + kh + c0, lk +(bo0>>1));
    gload16(qkvb  + kr1 + koff + kh + c1, lk +(bo1>>1));
    gload16(qkvjb + kr0 + koff + kh + c0, lkj+(bo0>>1));
    gload16(qkvjb + kr1 + koff + kh + c1, lkj+(bo1>>1));
    __syncthreads();
    const int kq = (lane>>4)<<3;
    const int ar = (wid>>1)*64 + (lane&15);
    const int bc = (wid&1)*64 + (lane&15);
    bf16x8 qf[4], qjf[4], kf[4], kjf[4];
    #pragma unroll
    for (int i = 0; i < 4; i++){
      qf[i]  = *(const bf16x8*)(lq  + (ar+i*16)*32 + kq);
      qjf[i] = *(const bf16x8*)(lqj + (ar+i*16)*32 + kq);
      kf[i]  = *(const bf16x8*)(lk  + (bc+i*16)*32 + kq);
      kjf[i] = *(const bf16x8*)(lkj + (bc+i*16)*32 + kq);
    }
    #pragma unroll
    for (int i = 0; i < 4; i++)
      #pragma unroll
      for (int j = 0; j < 4; j++){
        MFMA(accS[i][j], qf[i],  kf[j]);
        MFMA(accD[i][j], qjf[i], kf[j]);
        MFMA(accD[i][j], qf[i],  kjf[j]);
      }
    __syncthreads();
  }
  const int mb = mt*128 + (wid>>1)*64 + ((lane>>4)<<2);
  const int nb = nt*128 + (wid&1)*64 + (lane&15);
  u16* Sh = S   + (size_t)hz*SLEN*SLEN;
  u16* Dh = DMb + (size_t)hz*SLEN*SLEN;
  #pragma unroll
  for (int i = 0; i < 4; i++)
    #pragma unroll
    for (int j = 0; j < 4; j++)
      #pragma unroll
      for (int r = 0; r < 4; r++){
        const int m = mb + i*16 + r, n = nb + j*16;
        Sh[(size_t)m*SLEN+n] = f2bf(accS[i][j][r]*0.125f);
        Dh[(size_t)m*SLEN+n] = f2bf(accD[i][j][r]*0.125f);
      }
}

// ---------------- softmax + JVP filter, in place on score slabs -------------
__global__ __launch_bounds__(256) void softmax_filt_k(u16* __restrict__ S,
                                                      u16* __restrict__ DMb)
{
  const int m = blockIdx.x, hz = blockIdx.y;
  const int t = threadIdx.x, wid = t>>6, lane = t&63;
  u16* srow = S   + (size_t)hz*SLEN*SLEN + (size_t)m*SLEN;
  u16* drow = DMb + (size_t)hz*SLEN*SLEN + (size_t)m*SLEN;
  __shared__ __attribute__((aligned(64))) float sred[4];
  float s[4], dmv[4];
  const int i0 = t*4;
  #pragma unroll
  for (int e = 0; e < 4; e++){
    const int i = i0+e;
    const bool in = (i < NKV);
    s[e]   = in ? bf2f(srow[i]) : -1e30f;
    dmv[e] = in ? bf2f(drow[i]) : 0.0f;
  }
  float v = wmax(fmaxf(fmaxf(s[0],s[1]), fmaxf(s[2],s[3])));
  if (lane == 0) sred[wid] = v;
  __syncthreads();
  const float mx = fmaxf(fmaxf(sred[0],sred[1]), fmaxf(sred[2],sred[3]));
  __syncthreads();
  float p[4]; float ps = 0.f;
  #pragma unroll
  for (int e = 0; e < 4; e++){ p[e] = (i0+e < NKV) ? expf(s[e]-mx) : 0.f; ps += p[e]; }
  v = wsum(ps);
  if (lane == 0) sred[wid] = v;
  __syncthreads();
  const float l = sred[0]+sred[1]+sred[2]+sred[3];
  __syncthreads();
  const float rl = 1.0f/l;
  float a[4], f_[4]; float fs = 0.f;
  #pragma unroll
  for (int e = 0; e < 4; e++){ a[e] = p[e]*rl; f_[e] = dmv[e]*a[e]; fs += f_[e]; }
  v = wsum(fs);
  if (lane == 0) sred[wid] = v;
  __syncthreads();
  const float g = sred[0]+sred[1]+sred[2]+sred[3];
  #pragma unroll
  for (int e = 0; e < 4; e++){
    const int i = i0+e;
    if (i < SLEN){ srow[i] = f2bf(a[e]); drow[i] = f2bf(f_[e] - g*a[e]); }
  }
}

// ---------------- V transpose: vT[bh][d][kv] (zero-padded kv>=785) ----------
__global__ __launch_bounds__(256) void transpose_v_k(
    const u16* __restrict__ qkvb, const u16* __restrict__ qkvjb,
    u16* __restrict__ vT, u16* __restrict__ vjT)
{
  __shared__ __attribute__((aligned(64))) u16 tl[64][80];
  __shared__ __attribute__((aligned(64))) u16 tlj[64][80];
  const int kt = blockIdx.x, bh = blockIdx.y;
  const int b = bh>>4, h = bh&15;
  const int t = threadIdx.x;
  const int kv = t>>2, dd = (t&3)*16;
  const int kvg = kt*64 + kv;
  if (kvg < NKV){
    const u16* s0 = qkvb  + (size_t)(b*NKV+kvg)*H3C + 2048 + h*64 + dd;
    const u16* s1 = qkvjb + (size_t)(b*NKV+kvg)*H3C + 2048 + h*64 + dd;
    *(uint4*)&tl [kv][dd]   = *(const uint4*)s0;
    *(uint4*)&tl [kv][dd+8] = *(const uint4*)(s0+8);
    *(uint4*)&tlj[kv][dd]   = *(const uint4*)s1;
    *(uint4*)&tlj[kv][dd+8] = *(const uint4*)(s1+8);
  } else {
    uint4 z = {0,0,0,0};
    *(uint4*)&tl [kv][dd] = z; *(uint4*)&tl [kv][dd+8] = z;
    *(uint4*)&tlj[kv][dd] = z; *(uint4*)&tlj[kv][dd+8] = z;
  }
  __syncthreads();
  const int d = t>>2, kc = (t&3)*16;
  u16* d0 = vT  + ((size_t)bh*64 + d)*SLEN + kt*64 + kc;
  u16* d1 = vjT + ((size_t)bh*64 + d)*SLEN + kt*64 + kc;
  #pragma unroll
  for (int e = 0; e < 16; e++){ d0[e] = tl[kc+e][d]; d1[e] = tlj[kc+e][d]; }
}

// ---------------- PV: out = attn*V, out_j = filt*V + attn*Vj ----------------
__global__ __launch_bounds__(256) void attn_pv_k(
    const u16* __restrict__ S, const u16* __restrict__ DMb,
    const u16* __restrict__ vT, const u16* __restrict__ vjT,
    int bh0, int hbase, int bbase,
    u16* __restrict__ o, u16* __restrict__ oj)
{
  __shared__ __attribute__((aligned(64))) u16 lA[128*32];
  __shared__ __attribute__((aligned(64))) u16 lAj[128*32];
  __shared__ __attribute__((aligned(64))) u16 lB[64*32];
  __shared__ __attribute__((aligned(64))) u16 lBj[64*32];
  const int tid = threadIdx.x, wid = tid>>6, lane = tid&63;
  const int mt = blockIdx.x, hz = blockIdx.y;
  const u16* Ab  = S   + (size_t)hz*SLEN*SLEN;
  const u16* Ajb = DMb + (size_t)hz*SLEN*SLEN;
  const u16* Bb  = vT  + (size_t)(bh0+hz)*64*SLEN;
  const u16* Bjb = vjT + (size_t)(bh0+hz)*64*SLEN;
  f32x4 accO[4][2], accJ[4][2];
  #pragma unroll
  for (int i = 0; i < 4; i++)
    #pragma unroll
    for (int j = 0; j < 2; j++){
      accO[i][j] = (f32x4){0.f,0.f,0.f,0.f};
      accJ[i][j] = (f32x4){0.f,0.f,0.f,0.f};
    }
  const int m0 = mt*128;
  const int bo0 = wid*1024 + lane*16, bo1 = bo0 + 4096;
  const int r0 = bo0>>6, c0 = (bo0&63)>>1;
  const int r1 = bo1>>6, c1 = (bo1&63)>>1;
  const int bob = tid*16;
  const int rb = bob>>6, cb = (bob&63)>>1;
  for (int k0 = 0; k0 < SLEN; k0 += 32){
    gload16(Ab  + (size_t)(m0+r0)*SLEN + c0 + k0, lA +(bo0>>1));
    gload16(Ab  + (size_t)(m0+r1)*SLEN + c1 + k0, lA +(bo1>>1));
    gload16(Ajb + (size_t)(m0+r0)*SLEN + c0 + k0, lAj+(bo0>>1));
    gload16(Ajb + (size_t)(m0+r1)*SLEN + c1 + k0, lAj+(bo1>>1));
    gload16(Bb  + (size_t)rb*SLEN + cb + k0, lB +(bob>>1));
    gload16(Bjb + (size_t)rb*SLEN + cb + k0, lBj+(bob>>1));
    __syncthreads();
    const int kq = (lane>>4)<<3;
    const int ar = (wid>>1)*64 + (lane&15);
    const int bc = (wid&1)*32 + (lane&15);
    bf16x8 af[4], ajf[4], bbf[2], bjf[2];
    #pragma unroll
    for (int i = 0; i < 4; i++){
      af[i]  = *(const bf16x8*)(lA  + (ar+i*16)*32 + kq);
      ajf[i] = *(const bf16x8*)(lAj + (ar+i*16)*32 + kq);
    }
    #pragma unroll
    for (int j = 0; j < 2; j++){
      bbf[j] = *(const bf16x8*)(lB  + (bc+j*16)*32 + kq);
      bjf[j] = *(const bf16x8*)(lBj + (bc+j*16)*32 + kq);
    }
    #pragma unroll
    for (int i = 0; i < 4; i++)
      #pragma unroll
      for (int j = 0; j < 2; j++){
        MFMA(accO[i][j], af[i],  bbf[j]);
        MFMA(accJ[i][j], ajf[i], bbf[j]);
        MFMA(accJ[i][j], af[i],  bjf[j]);
      }
    __syncthreads();
  }
  const int mb = mt*128 + (wid>>1)*64 + ((lane>>4)<<2);
  const int nb = (wid&1)*32 + (lane&15);
  #pragma unroll
  for (int i = 0; i < 4; i++)
    #pragma unroll
    for (int j = 0; j < 2; j++)
      #pragma unroll
      for (int r = 0; r < 4; r++){
        const int m = mb + i*16 + r, n = nb + j*16;
        if (m < NKV){
          const size_t offo = (size_t)(bbase+m)*DIMC + (hbase+hz)*64 + n;
          o [offo] = f2bf(accO[i][j][r]);
          oj[offo] = f2bf(accJ[i][j][r]);
        }
      }
}

// ---------------------------------------------------------------------------
extern "C" void kernel_launch(void* const* d_in, const int* in_sizes, int n_in,
                              void* d_out, int out_size, void* d_ws, size_t ws_size,
                              hipStream_t stream)
{
  (void)in_sizes; (void)n_in; (void)out_size;
  const float* input   = (const float*)d_in[0];
  const float* inputj  = (const float*)d_in[1];
  const float* n1_w    = (const float*)d_in[2];
  const float* n1_b    = (const float*)d_in[3];
  const float* n1_lw   = (const float*)d_in[4];
  const float* n1_lb   = (const float*)d_in[5];
  const float* qkv_w   = (const float*)d_in[6];
  const float* qkv_lw  = (const float*)d_in[7];
  const float* proj_w  = (const float*)d_in[8];
  const float* proj_b  = (const float*)d_in[9];
  const float* proj_lw = (const float*)d_in[10];
  const float* proj_lb = (const float*)d_in[11];
  const float* n2_w    = (const float*)d_in[12];
  const float* n2_b    = (const float*)d_in[13];
  const float* n2_lw   = (const float*)d_in[14];
  const float* n2_lb   = (const float*)d_in[15];
  const float* fc1_w   = (const float*)d_in[16];
  const float* fc1_b   = (const float*)d_in[17];
  const float* fc1_lw  = (const float*)d_in[18];
  const float* fc1_lb  = (const float*)d_in[19];
  const float* fc2_w   = (const float*)d_in[20];
  const float* fc2_b   = (const float*)d_in[21];
  const float* fc2_lw  = (const float*)d_in[22];
  const float* fc2_lb  = (const float*)d_in[23];

  // ---- lifetime-overlapped workspace layout (bytes) ----
  const size_t SZ_W      = 2u*4194304u*2u;                 // 16.78 MB (2x max weight)
  const size_t SZ_ARENA1 = 2u*(size_t)MP*HIDC*2u;          // 54.53 MB (qkv pair -> h pair)
  const size_t SZ_VT     = (size_t)64*64*SLEN*2u;          //  7.34 MB
  const size_t SZ_SB     = (size_t)4*SLEN*SLEN*2u;         //  6.42 MB (4-head slab)
  const size_t SZ_ARENA2 = 2u*SZ_VT + 2u*SZ_SB;            // 27.53 MB (vT+S -> x3 pair)
  const size_t SZ_ARENA3 = 2u*(size_t)MP*DIMC*2u;          // 13.63 MB (x1 pair -> o pair)
  const size_t SZ_X2     = (size_t)MP*DIMC*4u;             // 13.63 MB each
  const size_t NEEDED = SZ_W + SZ_ARENA1 + SZ_ARENA2 + SZ_ARENA3 + 2u*SZ_X2 + 4096u;
  if (ws_size < NEEDED) return;   // diagnosable failure instead of a fault

  char* base = (char*)d_ws;
  size_t off = 0;
  auto ab = [&](size_t bytes)->char*{
    char* p = base + off;
    off += bytes; off = (off + 255) & ~(size_t)255;
    return p;
  };
  char* Wslot  = ab(SZ_W);
  char* arena1 = ab(SZ_ARENA1);
  char* arena2 = ab(SZ_ARENA2);
  char* arena3 = ab(SZ_ARENA3);
  float* x2  = (float*)ab(SZ_X2);
  float* x2j = (float*)ab(SZ_X2);

  u16* wbuf  = (u16*)Wslot;
  u16* wjbuf = wbuf + 4194304;            // element offset (max weight elems)
  u16* qkvb  = (u16*)arena1;
  u16* qkvjb = qkvb + (size_t)MP*H3C;
  u16* hb    = (u16*)arena1;              // after attention: reuse for fc1 out
  u16* hjb   = hb + (size_t)MP*HIDC;
  u16* vT    = (u16*)arena2;
  u16* vjT   = vT + (size_t)64*64*SLEN;
  u16* Sb    = vjT + (size_t)64*64*SLEN;
  u16* DMb   = Sb + (size_t)4*SLEN*SLEN;
  u16* x3b   = (u16*)arena2;              // after attention: reuse for ln2 out
  u16* x3jb  = x3b + (size_t)MP*DIMC;
  u16* x1b   = (u16*)arena3;
  u16* x1jb  = x1b + (size_t)MP*DIMC;
  u16* ob    = (u16*)arena3;              // after qkv gemm: reuse for attn out
  u16* ojb   = ob + (size_t)MP*DIMC;

  auto cvt = [&](const float* src, u16* dst, int n){
    cvt_k<<<dim3((n + 1023)/1024), 256, 0, stream>>>(src, dst, n);
  };

  // LN1
  ln_jvp_k<<<dim3(MP), 256, 0, stream>>>(input, inputj, n1_w, n1_b, n1_lw, n1_lb,
                                         x1b, x1jb);
  // QKV (no bias)
  cvt(qkv_w, wbuf, H3C*DIMC); cvt(qkv_lw, wjbuf, H3C*DIMC);
  gemm_jvp_k<0><<<dim3(H3C/128, MP/128), 256, 0, stream>>>(
      x1b, x1jb, DIMC, wbuf, wjbuf, DIMC, nullptr, nullptr, nullptr, nullptr,
      qkvb, qkvjb, H3C, MP);
  // V transpose (all 64 head-batches)
  transpose_v_k<<<dim3(14, 64), 256, 0, stream>>>(qkvb, qkvjb, vT, vjT);
  // attention, chunked by (batch, 4-head group); score slabs reused
  for (int c = 0; c < 4; c++)
    for (int g = 0; g < 4; g++){
      attn_scores_k<<<dim3(7, 7, 4), 256, 0, stream>>>(qkvb, qkvjb, c*NKV, g*4,
                                                       Sb, DMb);
      softmax_filt_k<<<dim3(NKV, 4), 256, 0, stream>>>(Sb, DMb);
      attn_pv_k<<<dim3(7, 4), 256, 0, stream>>>(Sb, DMb, vT, vjT,
                                                c*16 + g*4, g*4, c*NKV, ob, ojb);
    }
  // proj + residual(input) -> x2 fp32
  cvt(proj_w, wbuf, DIMC*DIMC); cvt(proj_lw, wjbuf, DIMC*DIMC);
  gemm_jvp_k<1><<<dim3(DIMC/128, MP/128), 256, 0, stream>>>(
      ob, ojb, DIMC, wbuf, wjbuf, DIMC, proj_b, proj_lb, input, inputj,
      x2, x2j, DIMC, MREAL);
  // LN2
  ln_jvp_k<<<dim3(MP), 256, 0, stream>>>(x2, x2j, n2_w, n2_b, n2_lw, n2_lb,
                                         x3b, x3jb);
  // FC1 + GELU-JVP
  cvt(fc1_w, wbuf, HIDC*DIMC); cvt(fc1_lw, wjbuf, HIDC*DIMC);
  gemm_jvp_k<2><<<dim3(HIDC/128, MP/128), 256, 0, stream>>>(
      x3b, x3jb, DIMC, wbuf, wjbuf, DIMC, fc1_b, fc1_lb, nullptr, nullptr,
      hb, hjb, HIDC, MP);
  // FC2 + residual(x2) -> d_out (out0, out1 concatenated)
  cvt(fc2_w, wbuf, DIMC*HIDC); cvt(fc2_lw, wjbuf, DIMC*HIDC);
  float* out0 = (float*)d_out;
  float* out1 = out0 + (size_t)MREAL*DIMC;
  gemm_jvp_k<1><<<dim3(DIMC/128, MP/128), 256, 0, stream>>>(
      hb, hjb, HIDC, wbuf, wjbuf, HIDC, fc2_b, fc2_lb, x2, x2j,
      out0, out1, DIMC, MREAL);
}

// Round 3
// 835.114 us; speedup vs baseline: 1.8008x; 1.8008x over previous
//
#include <hip/hip_runtime.h>
#include <hip/hip_bf16.h>

typedef unsigned short u16;
typedef unsigned int   u32;

#define MP     3328          // padded token rows (26*128)
#define MREAL  3140          // B*N = 4*785
#define DIMC   1024
#define H3C    3072
#define HIDC   4096
#define NKV    785
#define SLEN   896           // padded V^T row length (7*128)

typedef __bf16 bf16x8 __attribute__((ext_vector_type(8)));
typedef float  f32x4  __attribute__((ext_vector_type(4)));

#define MFMA(d,a,b) (d) = __builtin_amdgcn_mfma_f32_16x16x32_bf16((a),(b),(d),0,0,0)

__device__ __forceinline__ u16 f2bf(float f){
  u32 u = __builtin_bit_cast(u32, f);
  return (u16)((u + 0x7fffu + ((u >> 16) & 1u)) >> 16);
}
__device__ __forceinline__ float bf2f(u16 h){
  return __builtin_bit_cast(float, (u32)h << 16);
}
__device__ __forceinline__ void gload16(const u16* g, u16* l){
  __builtin_amdgcn_global_load_lds(
      (const __attribute__((address_space(1))) void*)g,
      (__attribute__((address_space(3))) void*)l, 16, 0, 0);
}
__device__ __forceinline__ float wsum(float v){
  #pragma unroll
  for (int o = 32; o >= 1; o >>= 1) v += __shfl_xor(v, o);
  return v;
}

// ---------------- fp32 -> bf16 weight conversion ----------------
__global__ __launch_bounds__(256) void cvt_k(const float* __restrict__ in,
                                             u16* __restrict__ out, int n){
  int i = (blockIdx.x * 256 + threadIdx.x) * 4;
  if (i >= n) return;
  float4 v = *(const float4*)(in + i);
  ushort4 o4;
  o4.x = f2bf(v.x); o4.y = f2bf(v.y); o4.z = f2bf(v.z); o4.w = f2bf(v.w);
  *(ushort4*)(out + i) = o4;
}

// ---------------- LayerNorm + JVP (fp32 in -> bf16 out, zero pad rows) -----
__global__ __launch_bounds__(256) void ln_jvp_k(
    const float* __restrict__ x, const float* __restrict__ xj,
    const float* __restrict__ w, const float* __restrict__ b,
    const float* __restrict__ lw, const float* __restrict__ lb,
    u16* __restrict__ out, u16* __restrict__ outj)
{
  const int row = blockIdx.x, t = threadIdx.x;
  const size_t ro = (size_t)row * DIMC;
  if (row >= MREAL){
    for (int i = t; i < DIMC; i += 256){ out[ro+i] = 0; outj[ro+i] = 0; }
    return;
  }
  const float4 v  = ((const float4*)(x  + ro))[t];
  const float4 vj = ((const float4*)(xj + ro))[t];
  float sx  = v.x+v.y+v.z+v.w;
  float sxx = v.x*v.x+v.y*v.y+v.z*v.z+v.w*v.w;
  float sj  = vj.x+vj.y+vj.z+vj.w;
  float sxj = v.x*vj.x+v.y*vj.y+v.z*vj.z+v.w*vj.w;
  __shared__ __attribute__((aligned(64))) float red[4][4];
  sx = wsum(sx); sxx = wsum(sxx); sj = wsum(sj); sxj = wsum(sxj);
  const int wid = t>>6, lane = t&63;
  if (lane == 0){ red[wid][0]=sx; red[wid][1]=sxx; red[wid][2]=sj; red[wid][3]=sxj; }
  __syncthreads();
  sx  = red[0][0]+red[1][0]+red[2][0]+red[3][0];
  sxx = red[0][1]+red[1][1]+red[2][1]+red[3][1];
  sj  = red[0][2]+red[1][2]+red[2][2]+red[3][2];
  sxj = red[0][3]+red[1][3]+red[2][3]+red[3][3];
  const float inv  = 1.0f/1024.0f;
  const float mean = sx*inv, meanj = sj*inv;
  const float var  = sxx*inv - mean*mean;
  const float cov  = sxj*inv - mean*meanj;       // mean(xc*xjc)
  const float rstd = rsqrtf(var + 1e-5f);
  const float r3   = rstd*rstd*rstd;
  const float4 wv  = ((const float4*)w)[t];
  const float4 bv  = ((const float4*)b)[t];
  const float4 lwv = ((const float4*)lw)[t];
  const float4 lbv = ((const float4*)lb)[t];
  const float xs[4]  = {v.x,v.y,v.z,v.w},   xjs[4] = {vj.x,vj.y,vj.z,vj.w};
  const float wss[4] = {wv.x,wv.y,wv.z,wv.w}, bs[4] = {bv.x,bv.y,bv.z,bv.w};
  const float lws[4] = {lwv.x,lwv.y,lwv.z,lwv.w}, lbs[4] = {lbv.x,lbv.y,lbv.z,lbv.w};
  const int i0 = t*4;
  #pragma unroll
  for (int e = 0; e < 4; e++){
    const float xc = xs[e]-mean, xjc = xjs[e]-meanj;
    const float xhat = xc*rstd;
    const float cc = xjc*rstd - xc*cov*r3;       // == (1/std^2)(a - bterm)
    out [ro+i0+e] = f2bf(xhat*wss[e] + bs[e]);
    outj[ro+i0+e] = f2bf(xhat*lws[e] + lbs[e] + cc*wss[e]);
  }
}

// ---------------- fused JVP GEMM: Y = A*B^T (+epi), Yj = Aj*B^T + A*Bj^T ----
template<int EPI>
__global__ __launch_bounds__(256) void gemm_jvp_k(
    const u16* __restrict__ A, const u16* __restrict__ Aj, int lda,
    const u16* __restrict__ B, const u16* __restrict__ Bj, int K,
    const float* __restrict__ bias, const float* __restrict__ biasj,
    const float* __restrict__ res, const float* __restrict__ resj,
    void* __restrict__ Yv, void* __restrict__ Yjv, int ldy, int mwrite)
{
  __shared__ __attribute__((aligned(64))) u16 lA[128*32];
  __shared__ __attribute__((aligned(64))) u16 lAj[128*32];
  __shared__ __attribute__((aligned(64))) u16 lB[128*32];
  __shared__ __attribute__((aligned(64))) u16 lBj[128*32];
  const int tid = threadIdx.x, wid = tid>>6, lane = tid&63;
  const int m0 = blockIdx.y*128, n0 = blockIdx.x*128;
  f32x4 accY[4][4], accJ[4][4];
  #pragma unroll
  for (int i = 0; i < 4; i++)
    #pragma unroll
    for (int j = 0; j < 4; j++){
      accY[i][j] = (f32x4){0.f,0.f,0.f,0.f};
      accJ[i][j] = (f32x4){0.f,0.f,0.f,0.f};
    }
  const int bo0 = wid*1024 + lane*16;     // staging byte offset, round 0
  const int bo1 = bo0 + 4096;             // round 1
  const int r0 = bo0>>6, c0 = (bo0&63)>>1;
  const int r1 = bo1>>6, c1 = (bo1&63)>>1;
  const u16* A0  = A  + (size_t)(m0+r0)*lda + c0;
  const u16* A1  = A  + (size_t)(m0+r1)*lda + c1;
  const u16* Aj0 = Aj + (size_t)(m0+r0)*lda + c0;
  const u16* Aj1 = Aj + (size_t)(m0+r1)*lda + c1;
  const u16* B0  = B  + (size_t)(n0+r0)*K + c0;
  const u16* B1  = B  + (size_t)(n0+r1)*K + c1;
  const u16* Bj0 = Bj + (size_t)(n0+r0)*K + c0;
  const u16* Bj1 = Bj + (size_t)(n0+r1)*K + c1;
  for (int k0 = 0; k0 < K; k0 += 32){
    gload16(A0 +k0, lA +(bo0>>1));
    gload16(A1 +k0, lA +(bo1>>1));
    gload16(Aj0+k0, lAj+(bo0>>1));
    gload16(Aj1+k0, lAj+(bo1>>1));
    gload16(B0 +k0, lB +(bo0>>1));
    gload16(B1 +k0, lB +(bo1>>1));
    gload16(Bj0+k0, lBj+(bo0>>1));
    gload16(Bj1+k0, lBj+(bo1>>1));
    __syncthreads();
    const int kq = (lane>>4)<<3;
    const int ar = (wid>>1)*64 + (lane&15);
    const int bc = (wid&1)*64 + (lane&15);
    bf16x8 af[4], ajf[4], bbf[4], bjf[4];
    #pragma unroll
    for (int i = 0; i < 4; i++){
      af[i]  = *(const bf16x8*)(lA  + (ar+i*16)*32 + kq);
      ajf[i] = *(const bf16x8*)(lAj + (ar+i*16)*32 + kq);
      bbf[i] = *(const bf16x8*)(lB  + (bc+i*16)*32 + kq);
      bjf[i] = *(const bf16x8*)(lBj + (bc+i*16)*32 + kq);
    }
    #pragma unroll
    for (int i = 0; i < 4; i++)
      #pragma unroll
      for (int j = 0; j < 4; j++){
        MFMA(accY[i][j], af[i],  bbf[j]);
        MFMA(accJ[i][j], ajf[i], bbf[j]);
        MFMA(accJ[i][j], af[i],  bjf[j]);
      }
    __syncthreads();
  }
  const int mb = m0 + (wid>>1)*64 + ((lane>>4)<<2);
  const int nb = n0 + (wid&1)*64 + (lane&15);
  #pragma unroll
  for (int i = 0; i < 4; i++)
    #pragma unroll
    for (int j = 0; j < 4; j++)
      #pragma unroll
      for (int r = 0; r < 4; r++){
        const int m = mb + i*16 + r, n = nb + j*16;
        float y = accY[i][j][r], yj = accJ[i][j][r];
        if (EPI == 0){
          ((u16*)Yv )[(size_t)m*ldy+n] = f2bf(y);
          ((u16*)Yjv)[(size_t)m*ldy+n] = f2bf(yj);
        } else if (EPI == 1){
          if (m < mwrite){
            y  += bias[n]  + res [(size_t)m*ldy+n];
            yj += biasj[n] + resj[(size_t)m*ldy+n];
            ((float*)Yv )[(size_t)m*ldy+n] = y;
            ((float*)Yjv)[(size_t)m*ldy+n] = yj;
          }
        } else {
          y  += bias[n];
          yj += biasj[n];
          const float ge  = 0.5f*y*(1.0f + erff(y*0.70710678118654752f));
          const float pdf = expf(-0.5f*y*y)*0.3989422804014327f;
          const float gj  = yj*(ge/(y + 1e-8f) + y*pdf);
          ((u16*)Yv )[(size_t)m*ldy+n] = f2bf(ge);
          ((u16*)Yjv)[(size_t)m*ldy+n] = f2bf(gj);
        }
      }
}

// ---------------- V transpose: vT[bh][d][kv] (zero-padded kv>=785) ----------
__global__ __launch_bounds__(256) void transpose_v_k(
    const u16* __restrict__ qkvb, const u16* __restrict__ qkvjb,
    u16* __restrict__ vT, u16* __restrict__ vjT)
{
  __shared__ __attribute__((aligned(64))) u16 tl[64][80];
  __shared__ __attribute__((aligned(64))) u16 tlj[64][80];
  const int kt = blockIdx.x, bh = blockIdx.y;
  const int b = bh>>4, h = bh&15;
  const int t = threadIdx.x;
  const int kv = t>>2, dd = (t&3)*16;
  const int kvg = kt*64 + kv;
  if (kvg < NKV){
    const u16* s0 = qkvb  + (size_t)(b*NKV+kvg)*H3C + 2048 + h*64 + dd;
    const u16* s1 = qkvjb + (size_t)(b*NKV+kvg)*H3C + 2048 + h*64 + dd;
    *(uint4*)&tl [kv][dd]   = *(const uint4*)s0;
    *(uint4*)&tl [kv][dd+8] = *(const uint4*)(s0+8);
    *(uint4*)&tlj[kv][dd]   = *(const uint4*)s1;
    *(uint4*)&tlj[kv][dd+8] = *(const uint4*)(s1+8);
  } else {
    uint4 z = {0,0,0,0};
    *(uint4*)&tl [kv][dd] = z; *(uint4*)&tl [kv][dd+8] = z;
    *(uint4*)&tlj[kv][dd] = z; *(uint4*)&tlj[kv][dd+8] = z;
  }
  __syncthreads();
  const int d = t>>2, kc = (t&3)*16;
  u16* d0 = vT  + ((size_t)bh*64 + d)*SLEN + kt*64 + kc;
  u16* d1 = vjT + ((size_t)bh*64 + d)*SLEN + kt*64 + kc;
  #pragma unroll
  for (int e = 0; e < 16; e++){ d0[e] = tl[kc+e][d]; d1[e] = tlj[kc+e][d]; }
}

// ---------------- fused flash-style JVP attention ---------------------------
// Block: 256 thr (4 waves), Q-tile 128 rows x 64 d, one (b,h). 13 kv-tiles x64.
// Online state per q-row: m (max), l (sum p), g (sum p*dm).
// Accumulators: PO = sum p*v ; PTJ = sum (p*dm)*v + p*vj.
// out = PO/l ; out_j = PTJ/l - (g/l)*(PO/l).
__global__ __launch_bounds__(256) void flash_attn_jvp_k(
    const u16* __restrict__ qkvb, const u16* __restrict__ qkvjb,
    const u16* __restrict__ vT, const u16* __restrict__ vjT,
    u16* __restrict__ o, u16* __restrict__ oj)
{
  __shared__ __attribute__((aligned(64))) u16 lK  [64*64];
  __shared__ __attribute__((aligned(64))) u16 lKj [64*64];
  __shared__ __attribute__((aligned(64))) u16 lvT [64*64];
  __shared__ __attribute__((aligned(64))) u16 lvjT[64*64];
  __shared__ __attribute__((aligned(64))) u16 pl  [128*64];
  __shared__ __attribute__((aligned(64))) u16 pdl [128*64];
  const int tid = threadIdx.x, wid = tid>>6, lane = tid&63;
  const int l4 = lane>>4, l15 = lane&15;
  const int qt = blockIdx.x, bh = blockIdx.y, b = bh>>4, h = bh&15;

  // Q fragments (A-operand layout): rows = qt*128 + wid*32 + i*16 + l15
  bf16x8 qf[2][2], qjf[2][2];
  {
    const size_t qrb = (size_t)b*NKV + qt*128 + wid*32;
    #pragma unroll
    for (int i = 0; i < 2; i++){
      const size_t ro = (qrb + i*16 + l15)*H3C + h*64;
      #pragma unroll
      for (int ks = 0; ks < 2; ks++){
        qf [i][ks] = *(const bf16x8*)(qkvb  + ro + ks*32 + l4*8);
        qjf[i][ks] = *(const bf16x8*)(qkvjb + ro + ks*32 + l4*8);
      }
    }
  }
  float m_st[2][4], l_st[2][4], g_st[2][4];
  f32x4 PO[2][4], PTJ[2][4];
  #pragma unroll
  for (int i = 0; i < 2; i++)
    #pragma unroll
    for (int r = 0; r < 4; r++){
      m_st[i][r] = -1e30f; l_st[i][r] = 0.f; g_st[i][r] = 0.f;
    }
  #pragma unroll
  for (int i = 0; i < 2; i++)
    #pragma unroll
    for (int j = 0; j < 4; j++){
      PO[i][j] = (f32x4){0.f,0.f,0.f,0.f};
      PTJ[i][j] = (f32x4){0.f,0.f,0.f,0.f};
    }
  const char* lKb   = (const char*)lK;
  const char* lKjb  = (const char*)lKj;
  const char* lvTb  = (const char*)lvT;
  const char* lvjTb = (const char*)lvjT;
  char* plb  = (char*)pl;
  char* pdlb = (char*)pdl;

  for (int t = 0; t < 13; t++){
    // ---- stage K/Kj (kv x d) and vT/vjT (d x kv), source-pre-swizzled ----
    #pragma unroll
    for (int rnd = 0; rnd < 2; rnd++){
      const int gidx = rnd*256 + tid;          // granule 0..511 (16B each)
      const int row = gidx>>3, c = gidx&7;
      const int cs = c ^ (row&7);
      const size_t ksrc = (size_t)(b*NKV + t*64 + row)*H3C + 1024 + h*64 + cs*8;
      gload16(qkvb  + ksrc, lK  + gidx*8);
      gload16(qkvjb + ksrc, lKj + gidx*8);
      const size_t vsrc = ((size_t)bh*64 + row)*SLEN + t*64 + cs*8;
      gload16(vT  + vsrc, lvT  + gidx*8);
      gload16(vjT + vsrc, lvjT + gidx*8);
    }
    __syncthreads();

    // ---- per 16-row strip: S/DM MFMA, online softmax, p/pdm -> LDS ----
    #pragma unroll
    for (int i = 0; i < 2; i++){
      f32x4 s[4], dm[4];
      #pragma unroll
      for (int j = 0; j < 4; j++){
        s[j] = (f32x4){0.f,0.f,0.f,0.f};
        dm[j] = (f32x4){0.f,0.f,0.f,0.f};
      }
      #pragma unroll
      for (int ks = 0; ks < 2; ks++){
        #pragma unroll
        for (int j = 0; j < 4; j++){
          const int row = j*16 + l15;
          const int byt = (row*128 + ks*64 + l4*16) ^ ((row&7)<<4);
          const bf16x8 kf  = *(const bf16x8*)(lKb  + byt);
          const bf16x8 kjf = *(const bf16x8*)(lKjb + byt);
          MFMA(s[j],  qf[i][ks],  kf);
          MFMA(dm[j], qjf[i][ks], kf);
          MFMA(dm[j], qf[i][ks],  kjf);
        }
      }
      // scale + mask + row-max
      float tm[4] = {-1e30f,-1e30f,-1e30f,-1e30f};
      #pragma unroll
      for (int j = 0; j < 4; j++){
        const int colg = t*64 + j*16 + l15;
        #pragma unroll
        for (int r = 0; r < 4; r++){
          float sv = s[j][r]*0.125f;
          if (colg >= NKV) sv = -1e30f;
          s[j][r] = sv;
          dm[j][r] *= 0.125f;
          tm[r] = fmaxf(tm[r], sv);
        }
      }
      #pragma unroll
      for (int r = 0; r < 4; r++){
        float v = tm[r];
        v = fmaxf(v, __shfl_xor(v, 1));
        v = fmaxf(v, __shfl_xor(v, 2));
        v = fmaxf(v, __shfl_xor(v, 4));
        v = fmaxf(v, __shfl_xor(v, 8));
        const float mn = fmaxf(m_st[i][r], v);
        const float sc = __expf(m_st[i][r] - mn);
        m_st[i][r] = mn;
        l_st[i][r] *= sc;
        g_st[i][r] *= sc;
        #pragma unroll
        for (int j = 0; j < 4; j++){ PO[i][j][r] *= sc; PTJ[i][j][r] *= sc; }
      }
      float ps[4] = {0.f,0.f,0.f,0.f}, pds[4] = {0.f,0.f,0.f,0.f};
      #pragma unroll
      for (int j = 0; j < 4; j++){
        const int col = j*16 + l15;
        #pragma unroll
        for (int r = 0; r < 4; r++){
          const float p  = __expf(s[j][r] - m_st[i][r]);
          const float pd = p * dm[j][r];
          ps[r] += p; pds[r] += pd;
          const int row = wid*32 + i*16 + l4*4 + r;
          const int byt = (row*128 + col*2) ^ ((row&7)<<4);
          *(u16*)(plb  + byt) = f2bf(p);
          *(u16*)(pdlb + byt) = f2bf(pd);
        }
      }
      #pragma unroll
      for (int r = 0; r < 4; r++){
        float v = ps[r], w = pds[r];
        v += __shfl_xor(v, 1); w += __shfl_xor(w, 1);
        v += __shfl_xor(v, 2); w += __shfl_xor(w, 2);
        v += __shfl_xor(v, 4); w += __shfl_xor(w, 4);
        v += __shfl_xor(v, 8); w += __shfl_xor(w, 8);
        l_st[i][r] += v; g_st[i][r] += w;
      }
    }

    // ---- PV: PO += p*vT ; PTJ += pdm*vT + p*vjT (wave-local p rows) ----
    #pragma unroll
    for (int ks = 0; ks < 2; ks++){
      bf16x8 pa[2], pda[2];
      #pragma unroll
      for (int i = 0; i < 2; i++){
        const int row = wid*32 + i*16 + l15;
        const int byt = (row*128 + ks*64 + l4*16) ^ ((row&7)<<4);
        pa[i]  = *(const bf16x8*)(plb  + byt);
        pda[i] = *(const bf16x8*)(pdlb + byt);
      }
      #pragma unroll
      for (int j = 0; j < 4; j++){
        const int row = j*16 + l15;                  // d index
        const int byt = (row*128 + ks*64 + l4*16) ^ ((row&7)<<4);
        const bf16x8 vb  = *(const bf16x8*)(lvTb  + byt);
        const bf16x8 vjb = *(const bf16x8*)(lvjTb + byt);
        #pragma unroll
        for (int i = 0; i < 2; i++){
          MFMA(PO[i][j],  pa[i],  vb);
          MFMA(PTJ[i][j], pda[i], vb);
          MFMA(PTJ[i][j], pa[i],  vjb);
        }
      }
    }
    __syncthreads();
  }

  // ---- epilogue ----
  #pragma unroll
  for (int i = 0; i < 2; i++)
    #pragma unroll
    for (int r = 0; r < 4; r++){
      const int ql = qt*128 + wid*32 + i*16 + l4*4 + r;
      if (ql < NKV){
        const float rl = 1.0f / l_st[i][r];
        const float gg = g_st[i][r] * rl;
        #pragma unroll
        for (int j = 0; j < 4; j++){
          const size_t oo = ((size_t)b*NKV + ql)*DIMC + h*64 + j*16 + l15;
          const float po = PO[i][j][r] * rl;
          o [oo] = f2bf(po);
          oj[oo] = f2bf(PTJ[i][j][r]*rl - gg*po);
        }
      }
    }
}

// ---------------------------------------------------------------------------
extern "C" void kernel_launch(void* const* d_in, const int* in_sizes, int n_in,
                              void* d_out, int out_size, void* d_ws, size_t ws_size,
                              hipStream_t stream)
{
  (void)in_sizes; (void)n_in; (void)out_size;
  const float* input   = (const float*)d_in[0];
  const float* inputj  = (const float*)d_in[1];
  const float* n1_w    = (const float*)d_in[2];
  const float* n1_b    = (const float*)d_in[3];
  const float* n1_lw   = (const float*)d_in[4];
  const float* n1_lb   = (const float*)d_in[5];
  const float* qkv_w   = (const float*)d_in[6];
  const float* qkv_lw  = (const float*)d_in[7];
  const float* proj_w  = (const float*)d_in[8];
  const float* proj_b  = (const float*)d_in[9];
  const float* proj_lw = (const float*)d_in[10];
  const float* proj_lb = (const float*)d_in[11];
  const float* n2_w    = (const float*)d_in[12];
  const float* n2_b    = (const float*)d_in[13];
  const float* n2_lw   = (const float*)d_in[14];
  const float* n2_lb   = (const float*)d_in[15];
  const float* fc1_w   = (const float*)d_in[16];
  const float* fc1_b   = (const float*)d_in[17];
  const float* fc1_lw  = (const float*)d_in[18];
  const float* fc1_lb  = (const float*)d_in[19];
  const float* fc2_w   = (const float*)d_in[20];
  const float* fc2_b   = (const float*)d_in[21];
  const float* fc2_lw  = (const float*)d_in[22];
  const float* fc2_lb  = (const float*)d_in[23];

  // ---- lifetime-overlapped workspace layout (bytes) ----
  const size_t SZ_W      = 2u*4194304u*2u;                 // 16.78 MB (2x max weight)
  const size_t SZ_ARENA1 = 2u*(size_t)MP*HIDC*2u;          // 54.53 MB (qkv pair -> h pair)
  const size_t SZ_VT     = (size_t)64*64*SLEN*2u;          //  7.34 MB
  const size_t SZ_ARENA2 = 2u*SZ_VT;                       // 14.68 MB (vT pair -> x3 pair)
  const size_t SZ_ARENA3 = 2u*(size_t)MP*DIMC*2u;          // 13.63 MB (x1 pair -> o pair)
  const size_t SZ_X2     = (size_t)MP*DIMC*4u;             // 13.63 MB each
  const size_t NEEDED = SZ_W + SZ_ARENA1 + SZ_ARENA2 + SZ_ARENA3 + 2u*SZ_X2 + 4096u;
  if (ws_size < NEEDED) return;   // diagnosable failure instead of a fault

  char* base = (char*)d_ws;
  size_t off = 0;
  auto ab = [&](size_t bytes)->char*{
    char* p = base + off;
    off += bytes; off = (off + 255) & ~(size_t)255;
    return p;
  };
  char* Wslot  = ab(SZ_W);
  char* arena1 = ab(SZ_ARENA1);
  char* arena2 = ab(SZ_ARENA2);
  char* arena3 = ab(SZ_ARENA3);
  float* x2  = (float*)ab(SZ_X2);
  float* x2j = (float*)ab(SZ_X2);

  u16* wbuf  = (u16*)Wslot;
  u16* wjbuf = wbuf + 4194304;            // element offset (max weight elems)
  u16* qkvb  = (u16*)arena1;
  u16* qkvjb = qkvb + (size_t)MP*H3C;
  u16* hb    = (u16*)arena1;              // after attention: reuse for fc1 out
  u16* hjb   = hb + (size_t)MP*HIDC;
  u16* vT    = (u16*)arena2;
  u16* vjT   = vT + (size_t)64*64*SLEN;
  u16* x3b   = (u16*)arena2;              // after attention: reuse for ln2 out
  u16* x3jb  = x3b + (size_t)MP*DIMC;
  u16* x1b   = (u16*)arena3;
  u16* x1jb  = x1b + (size_t)MP*DIMC;
  u16* ob    = (u16*)arena3;              // after qkv gemm: reuse for attn out
  u16* ojb   = ob + (size_t)MP*DIMC;

  auto cvt = [&](const float* src, u16* dst, int n){
    cvt_k<<<dim3((n + 1023)/1024), 256, 0, stream>>>(src, dst, n);
  };

  // LN1
  ln_jvp_k<<<dim3(MP), 256, 0, stream>>>(input, inputj, n1_w, n1_b, n1_lw, n1_lb,
                                         x1b, x1jb);
  // QKV (no bias)
  cvt(qkv_w, wbuf, H3C*DIMC); cvt(qkv_lw, wjbuf, H3C*DIMC);
  gemm_jvp_k<0><<<dim3(H3C/128, MP/128), 256, 0, stream>>>(
      x1b, x1jb, DIMC, wbuf, wjbuf, DIMC, nullptr, nullptr, nullptr, nullptr,
      qkvb, qkvjb, H3C, MP);
  // V transpose (all 64 head-batches)
  transpose_v_k<<<dim3(14, 64), 256, 0, stream>>>(qkvb, qkvjb, vT, vjT);
  // fused flash JVP attention: one launch, writes ob/ojb (aliases x1 arena)
  flash_attn_jvp_k<<<dim3(7, 64), 256, 0, stream>>>(qkvb, qkvjb, vT, vjT, ob, ojb);
  // proj + residual(input) -> x2 fp32
  cvt(proj_w, wbuf, DIMC*DIMC); cvt(proj_lw, wjbuf, DIMC*DIMC);
  gemm_jvp_k<1><<<dim3(DIMC/128, MP/128), 256, 0, stream>>>(
      ob, ojb, DIMC, wbuf, wjbuf, DIMC, proj_b, proj_lb, input, inputj,
      x2, x2j, DIMC, MREAL);
  // LN2
  ln_jvp_k<<<dim3(MP), 256, 0, stream>>>(x2, x2j, n2_w, n2_b, n2_lw, n2_lb,
                                         x3b, x3jb);
  // FC1 + GELU-JVP
  cvt(fc1_w, wbuf, HIDC*DIMC); cvt(fc1_lw, wjbuf, HIDC*DIMC);
  gemm_jvp_k<2><<<dim3(HIDC/128, MP/128), 256, 0, stream>>>(
      x3b, x3jb, DIMC, wbuf, wjbuf, DIMC, fc1_b, fc1_lb, nullptr, nullptr,
      hb, hjb, HIDC, MP);
  // FC2 + residual(x2) -> d_out (out0, out1 concatenated)
  cvt(fc2_w, wbuf, DIMC*HIDC); cvt(fc2_lw, wjbuf, DIMC*HIDC);
  float* out0 = (float*)d_out;
  float* out1 = out0 + (size_t)MREAL*DIMC;
  gemm_jvp_k<1><<<dim3(DIMC/128, MP/128), 256, 0, stream>>>(
      hb, hjb, HIDC, wbuf, wjbuf, HIDC, fc2_b, fc2_lb, x2, x2j,
      out0, out1, DIMC, MREAL);
}